// Round 8
// baseline (616.864 us; speedup 1.0000x reference)
//
#include <hip/hip_runtime.h>
#include <math.h>

// Problem constants (fixed by reference)
#define BATCH 4096
#define LNUM  4
#define NEIGH 32
#define FEAT  256
#define EMB   128
#define NODES 100000

#define B_TILE 4                 // batches per block
#define ROWS   (B_TILE * LNUM)   // 16 (b,l) rows per block

// ---------------------------------------------------------------------------
// Fused kernel (R4 structure), gather rewritten as a 3-deep software
// pipeline. Wave w owns batch b0+w: 4 layer-rows x 32 neighbors = 128
// full-row loads (one wave64 float4 load = 1 KB = one feature row), split
// into 16 chunks of 8. Three register buffers keep ~24 row-loads (~384
// cache lines) in flight per wave; consume(c) needs only vmcnt(16)-style
// partial waits. R4's VGPR_Count=48 proved the old loop kept only ~4-6
// loads live -- the actual limiter across R4-R7's null results.
// LDS: sS 16KB + sH 8KB -> occupancy VGPR-bound (~3 waves/SIMD), fine.
// ---------------------------------------------------------------------------
__global__ __launch_bounds__(256) void fused_liamne(
    const int* __restrict__ layers, const int* __restrict__ node_i,
    const int* __restrict__ neighs, const float* __restrict__ features,
    const float* __restrict__ layer_embs, const float* __restrict__ W,
    const float* __restrict__ Wt, const float* __restrict__ Ws1,
    const float* __restrict__ Ws2, float* __restrict__ out) {
  __shared__ float sS[ROWS][FEAT];   // 16 KB; reused as sAgg in P4
  __shared__ float sH[ROWS][EMB];    // 8 KB
  __shared__ float sc[ROWS];

  int b0 = blockIdx.x * B_TILE;
  int tid = threadIdx.x;
  int w = tid >> 6;       // wave index 0..3
  int lane = tid & 63;

  // ---- Phase 1: pipelined gather + neighbor-sum. Wave w owns batch b0+w.
  {
    int idx[LNUM];
#pragma unroll
    for (int l = 0; l < LNUM; ++l) {
      const int* nbr = neighs + ((size_t)(b0 + w) * LNUM + l) * NEIGH;
      idx[l] = nbr[lane & 31];  // lanes 0..31 hold the 32 indices
    }
    const float4* f4 = (const float4*)features;
    float4 acc[LNUM];
#pragma unroll
    for (int l = 0; l < LNUM; ++l) acc[l] = make_float4(0.f, 0.f, 0.f, 0.f);

    float4 buf[3][8];
    // chunk c (0..15): layer c>>2, neighbors (c&3)*8 .. +7
#define ISSUE(c, s)                                                     \
  {                                                                     \
    int l_ = (c) >> 2, j0_ = ((c) & 3) * 8;                             \
    _Pragma("unroll") for (int q = 0; q < 8; ++q) {                     \
      int n_ = __shfl(idx[l_], j0_ + q, 64);                            \
      buf[s][q] = f4[(size_t)n_ * (FEAT / 4) + lane];                   \
    }                                                                   \
  }
    ISSUE(0, 0);
    ISSUE(1, 1);
#pragma unroll
    for (int c = 0; c < 16; ++c) {
      if (c + 2 < 16) {
        int s = (c + 2) % 3;
        ISSUE(c + 2, s);
      }
      int l = c >> 2;
      int s = c % 3;
#pragma unroll
      for (int q = 0; q < 8; ++q) {
        acc[l].x += buf[s][q].x;
        acc[l].y += buf[s][q].y;
        acc[l].z += buf[s][q].z;
        acc[l].w += buf[s][q].w;
      }
    }
#undef ISSUE
#pragma unroll
    for (int l = 0; l < LNUM; ++l)
      ((float4*)sS[w * LNUM + l])[lane] = acc[l];
  }
  __syncthreads();

  // ---- Phase 2: sH[lb*4+w] = sS[lb*4+w] @ W[w], wave w == layer w --------
  {
    const float* Wl = W + (size_t)w * FEAT * EMB;
    float acc[B_TILE][2] = {};
    for (int k = 0; k < FEAT; k += 4) {
      float4 s[B_TILE];
#pragma unroll
      for (int lb = 0; lb < B_TILE; ++lb)
        s[lb] = *(const float4*)&sS[lb * LNUM + w][k];
#pragma unroll
      for (int kk = 0; kk < 4; ++kk) {
        float2 wv = *(const float2*)&Wl[(size_t)(k + kk) * EMB + lane * 2];
#pragma unroll
        for (int lb = 0; lb < B_TILE; ++lb) {
          float sv = ((const float*)&s[lb])[kk];
          acc[lb][0] += sv * wv.x;
          acc[lb][1] += sv * wv.y;
        }
      }
    }
#pragma unroll
    for (int lb = 0; lb < B_TILE; ++lb)
      *(float2*)&sH[lb * LNUM + w][lane * 2] =
          make_float2(acc[lb][0], acc[lb][1]);
  }
  __syncthreads();

  // ---- Phase 3: sc[r] = tanh(sH[r] @ Ws1) @ Ws2, rows w*4..w*4+3 ---------
  {
    float acc[4][2] = {};
    for (int k = 0; k < EMB; k += 4) {
      float4 h[4];
#pragma unroll
      for (int i = 0; i < 4; ++i)
        h[i] = *(const float4*)&sH[w * 4 + i][k];
#pragma unroll
      for (int kk = 0; kk < 4; ++kk) {
        float2 wv = *(const float2*)&Ws1[(size_t)(k + kk) * EMB + lane * 2];
#pragma unroll
        for (int i = 0; i < 4; ++i) {
          float hv = ((const float*)&h[i])[kk];
          acc[i][0] += hv * wv.x;
          acc[i][1] += hv * wv.y;
        }
      }
    }
    float2 w2 = *(const float2*)&Ws2[lane * 2];
#pragma unroll
    for (int i = 0; i < 4; ++i) {
      float p = tanhf(acc[i][0]) * w2.x + tanhf(acc[i][1]) * w2.y;
#pragma unroll
      for (int m = 1; m < 64; m <<= 1) p += __shfl_xor(p, m, 64);
      if (lane == 0) sc[w * 4 + i] = p;
    }
  }
  __syncthreads();

  // ---- Phase 4a: softmax + attention-weighted agg into sAgg (= sS) -------
  float* sAgg = &sS[0][0];  // B_TILE x EMB overlays dead sS
  for (int i = tid; i < B_TILE * EMB; i += 256) {
    int lb = i >> 7, m = i & 127;
    float s0 = sc[lb * 4 + 0], s1 = sc[lb * 4 + 1];
    float s2 = sc[lb * 4 + 2], s3 = sc[lb * 4 + 3];
    float mx = fmaxf(fmaxf(s0, s1), fmaxf(s2, s3));
    float e0 = expf(s0 - mx), e1 = expf(s1 - mx);
    float e2 = expf(s2 - mx), e3 = expf(s3 - mx);
    float inv = 1.0f / (e0 + e1 + e2 + e3);
    float a = e0 * sH[lb * 4 + 0][m] + e1 * sH[lb * 4 + 1][m] +
              e2 * sH[lb * 4 + 2][m] + e3 * sH[lb * 4 + 3][m];
    sAgg[i] = a * inv;
  }
  __syncthreads();

  // ---- Phase 4b: wave w: out[b0+w] = normalize(agg @ Wt + layer_emb) -----
  {
    float ax = 0.f, ay = 0.f;
    for (int k = 0; k < EMB; ++k) {
      float2 wv = *(const float2*)&Wt[(size_t)k * EMB + lane * 2];
      float a = sAgg[w * EMB + k];
      ax += a * wv.x;
      ay += a * wv.y;
    }
    int b = b0 + w;
    int node = node_i[b];
    int lay = layers[b];
    float2 e = *(const float2*)&layer_embs[((size_t)node * LNUM + lay) * EMB +
                                           lane * 2];
    ax += e.x;
    ay += e.y;
    float ss = ax * ax + ay * ay;
#pragma unroll
    for (int m = 1; m < 64; m <<= 1) ss += __shfl_xor(ss, m, 64);
    float inv = 1.0f / fmaxf(sqrtf(ss), 1e-12f);
    *(float2*)&out[(size_t)b * EMB + lane * 2] =
        make_float2(ax * inv, ay * inv);
  }
}

extern "C" void kernel_launch(void* const* d_in, const int* in_sizes, int n_in,
                              void* d_out, int out_size, void* d_ws,
                              size_t ws_size, hipStream_t stream) {
  const int* layers = (const int*)d_in[0];
  const int* node_i = (const int*)d_in[1];
  const int* neighs = (const int*)d_in[2];
  const float* features = (const float*)d_in[3];
  const float* layer_embs = (const float*)d_in[4];
  const float* neigh_emb_trans = (const float*)d_in[5];
  const float* trans_weights = (const float*)d_in[6];
  const float* trans_weights_s1 = (const float*)d_in[7];
  const float* trans_weights_s2 = (const float*)d_in[8];
  float* out = (float*)d_out;

  fused_liamne<<<dim3(BATCH / B_TILE), 256, 0, stream>>>(
      layers, node_i, neighs, features, layer_embs, neigh_emb_trans,
      trans_weights, trans_weights_s1, trans_weights_s2, out);
}